// Round 1
// baseline (430.828 us; speedup 1.0000x reference)
//
#include <hip/hip_runtime.h>

static constexpr float NEAR_T = 0.1f;
static constexpr float FAR_T  = 3.0f;

// One ray per 64-lane wave; 2 samples per lane (lane handles s=2*lane, 2*lane+1).
__global__ __launch_bounds__(256)
void plenoxel_render(const float* __restrict__ density,
                     const float* __restrict__ sh,
                     const float* __restrict__ origins,
                     const float* __restrict__ dirs,
                     const int*  __restrict__ ns_ptr,
                     float* __restrict__ out,
                     int nrays)
{
    const int lane = threadIdx.x & 63;
    const int ray  = (int)((blockIdx.x * blockDim.x + threadIdx.x) >> 6);
    if (ray >= nrays) return;   // wave-uniform

    const int ns = *ns_ptr;
    const float step = (FAR_T - NEAR_T) / (float)(ns - 1);

    const float ox = origins[ray*3+0];
    const float oy = origins[ray*3+1];
    const float oz = origins[ray*3+2];
    const float dx = dirs[ray*3+0];
    const float dy = dirs[ray*3+1];
    const float dz = dirs[ray*3+2];

    // Degree-2 SH basis from normalized direction (zero-guard like reference)
    float nx = dx, ny = dy, nz = dz;
    float nn = nx*nx + ny*ny + nz*nz;
    if (nn < 1e-8f) { nx = 0.0f; ny = 0.0f; nz = 1.0f; nn = 1.0f; }
    const float inv = 1.0f / sqrtf(nn);
    nx *= inv; ny *= inv; nz *= inv;

    float B0 = 0.282095f;
    float B1 = 0.488603f * ny;
    float B2 = 0.488603f * nz;
    float B3 = 0.488603f * nx;
    float B4 = 1.092548f * nx * ny;
    float B5 = 1.092548f * ny * nz;
    float B6 = 0.315392f * (3.0f * nz * nz - 1.0f);
    float B7 = 1.092548f * nx * nz;
    float B8 = 0.546274f * (nx * nx - ny * ny);

    float alpha[2];
    float rgbs[2][3];

    #pragma unroll
    for (int si = 0; si < 2; ++si) {
        const int s = 2*lane + si;
        if (s >= ns) {
            alpha[si] = 0.0f;
            rgbs[si][0] = rgbs[si][1] = rgbs[si][2] = 0.0f;
            continue;
        }
        const float t = NEAR_T + (float)s * step;
        float px = ox + t*dx;
        float py = oy + t*dy;
        float pz = oz + t*dz;
        // normalize to [-1,1] (scene bounds are [-1,1] -> identity mod rounding),
        // then voxel coords p = (n+1)*0.5*(dim-1)
        px = 2.0f*(px + 1.0f)*0.5f - 1.0f;
        py = 2.0f*(py + 1.0f)*0.5f - 1.0f;
        pz = 2.0f*(pz + 1.0f)*0.5f - 1.0f;
        const float pvx = (px + 1.0f) * 0.5f * 127.0f;
        const float pvy = (py + 1.0f) * 0.5f * 127.0f;
        const float pvz = (pz + 1.0f) * 0.5f * 127.0f;

        const float fx = floorf(pvx), fy = floorf(pvy), fz = floorf(pvz);
        const float frx = pvx - fx, fry = pvy - fy, frz = pvz - fz;
        const int x0 = (int)fminf(fmaxf(fx, 0.0f), 127.0f);
        const int y0 = (int)fminf(fmaxf(fy, 0.0f), 127.0f);
        const int z0 = (int)fminf(fmaxf(fz, 0.0f), 127.0f);
        const int x1 = (int)fminf(fmaxf(ceilf(pvx), 0.0f), 127.0f);
        const int y1 = (int)fminf(fmaxf(ceilf(pvy), 0.0f), 127.0f);
        const int z1 = (int)fminf(fmaxf(ceilf(pvz), 0.0f), 127.0f);

        const float wxv[2] = {1.0f - frx, frx};
        const float wyv[2] = {1.0f - fry, fry};
        const float wzv[2] = {1.0f - frz, frz};
        const int xb[2] = {x0 << 14, x1 << 14};
        const int yb[2] = {y0 << 7,  y1 << 7};
        const int zb[2] = {z0, z1};

        float sg = 0.0f, r0 = 0.0f, r1 = 0.0f, r2 = 0.0f;
        #pragma unroll
        for (int cx = 0; cx < 2; ++cx) {
            #pragma unroll
            for (int cy = 0; cy < 2; ++cy) {
                #pragma unroll
                for (int cz = 0; cz < 2; ++cz) {
                    const float w = wxv[cx] * wyv[cy] * wzv[cz];
                    const int base = xb[cx] + yb[cy] + zb[cz];
                    sg = fmaf(w, density[base], sg);
                    const float* sp = sh + (long long)base * 27;
                    #pragma unroll
                    for (int c = 0; c < 3; ++c) {
                        const float4 q0 = *(const float4*)(sp + c*9 + 0);
                        const float4 q1 = *(const float4*)(sp + c*9 + 4);
                        const float  e  = sp[c*9 + 8];
                        float dot = q0.x*B0 + q0.y*B1 + q0.z*B2 + q0.w*B3
                                  + q1.x*B4 + q1.y*B5 + q1.z*B6 + q1.w*B7
                                  + e*B8;
                        if (c == 0)      r0 = fmaf(w, dot, r0);
                        else if (c == 1) r1 = fmaf(w, dot, r1);
                        else             r2 = fmaf(w, dot, r2);
                    }
                }
            }
        }

        const float a = 1.0f - expf(-fmaxf(sg, 0.0f) * step);
        alpha[si] = a;
        rgbs[si][0] = 1.0f / (1.0f + expf(-r0));
        rgbs[si][1] = 1.0f / (1.0f + expf(-r1));
        rgbs[si][2] = 1.0f / (1.0f + expf(-r2));
    }

    // trans_s = prod_{j<s} a_j via wave-level product scan over lane-pairs
    const float a0 = (1.0f - alpha[0]) + 1e-10f;
    const float a1 = (1.0f - alpha[1]) + 1e-10f;

    float incl = a0 * a1;
    #pragma unroll
    for (int off = 1; off < 64; off <<= 1) {
        const float v = __shfl_up(incl, off, 64);
        incl = (lane >= off) ? incl * v : incl;
    }
    float excl = __shfl_up(incl, 1, 64);
    excl = (lane == 0) ? 1.0f : excl;

    const float t0 = excl;
    const float t1 = excl * a0;
    const float w0 = alpha[0] * t0;
    const float w1 = alpha[1] * t1;

    float cr = w0*rgbs[0][0] + w1*rgbs[1][0];
    float cg = w0*rgbs[0][1] + w1*rgbs[1][1];
    float cb = w0*rgbs[0][2] + w1*rgbs[1][2];

    #pragma unroll
    for (int off = 32; off; off >>= 1) {
        cr += __shfl_down(cr, off, 64);
        cg += __shfl_down(cg, off, 64);
        cb += __shfl_down(cb, off, 64);
    }

    if (lane == 0) {
        out[ray*3+0] = cr;
        out[ray*3+1] = cg;
        out[ray*3+2] = cb;
    }
}

extern "C" void kernel_launch(void* const* d_in, const int* in_sizes, int n_in,
                              void* d_out, int out_size, void* d_ws, size_t ws_size,
                              hipStream_t stream) {
    const float* density = (const float*)d_in[0];
    const float* sh      = (const float*)d_in[1];
    const float* origins = (const float*)d_in[2];
    const float* dirs    = (const float*)d_in[3];
    const int*   ns_ptr  = (const int*)d_in[4];
    float* out = (float*)d_out;

    const int nrays = in_sizes[2] / 3;
    const int threads = 256;                       // 4 rays per block
    const int blocks = (nrays * 64 + threads - 1) / threads;
    plenoxel_render<<<blocks, threads, 0, stream>>>(density, sh, origins, dirs,
                                                    ns_ptr, out, nrays);
}

// Round 2
// 343.565 us; speedup vs baseline: 1.2540x; 1.2540x over previous
//
#include <hip/hip_runtime.h>

static constexpr float NEAR_T = 0.1f;
static constexpr float FAR_T  = 3.0f;

// One ray per 64-lane wave; 2 samples per lane (lane handles s=2*lane, 2*lane+1).
// Phase A: density-only gather -> alpha -> wave product-scan -> per-sample weight.
// Phase B: SH gather ONLY for samples with weight > 0 (exact skip: w==0 -> no contribution).
__global__ __launch_bounds__(256)
void plenoxel_render(const float* __restrict__ density,
                     const float* __restrict__ sh,
                     const float* __restrict__ origins,
                     const float* __restrict__ dirs,
                     const int*  __restrict__ ns_ptr,
                     float* __restrict__ out,
                     int nrays)
{
    const int lane = threadIdx.x & 63;
    const int ray  = (int)((blockIdx.x * blockDim.x + threadIdx.x) >> 6);
    if (ray >= nrays) return;   // wave-uniform

    const int ns = *ns_ptr;
    const float step = (FAR_T - NEAR_T) / (float)(ns - 1);

    const float ox = origins[ray*3+0];
    const float oy = origins[ray*3+1];
    const float oz = origins[ray*3+2];
    const float dx = dirs[ray*3+0];
    const float dy = dirs[ray*3+1];
    const float dz = dirs[ray*3+2];

    // Degree-2 SH basis from normalized direction (zero-guard like reference)
    float nx = dx, ny = dy, nz = dz;
    float nn = nx*nx + ny*ny + nz*nz;
    if (nn < 1e-8f) { nx = 0.0f; ny = 0.0f; nz = 1.0f; nn = 1.0f; }
    const float inv = 1.0f / sqrtf(nn);
    nx *= inv; ny *= inv; nz *= inv;

    const float B0 = 0.282095f;
    const float B1 = 0.488603f * ny;
    const float B2 = 0.488603f * nz;
    const float B3 = 0.488603f * nx;
    const float B4 = 1.092548f * nx * ny;
    const float B5 = 1.092548f * ny * nz;
    const float B6 = 0.315392f * (3.0f * nz * nz - 1.0f);
    const float B7 = 1.092548f * nx * nz;
    const float B8 = 0.546274f * (nx * nx - ny * ny);

    // ---- Phase A: geometry + density-only gather -> alpha ----
    float alpha2[2];
    float frv[2][3];
    int xb2[2][2], yb2[2][2], zb2[2][2];

    #pragma unroll
    for (int si = 0; si < 2; ++si) {
        const int s = 2*lane + si;
        float sg = 0.0f;
        if (s < ns) {
            const float t = NEAR_T + (float)s * step;
            float px = ox + t*dx;
            float py = oy + t*dy;
            float pz = oz + t*dz;
            // match reference rounding: norm = 2*(p+1)*0.5 - 1 ; voxel = (n+1)*0.5*127
            px = 2.0f*(px + 1.0f)*0.5f - 1.0f;
            py = 2.0f*(py + 1.0f)*0.5f - 1.0f;
            pz = 2.0f*(pz + 1.0f)*0.5f - 1.0f;
            const float pvx = (px + 1.0f) * 0.5f * 127.0f;
            const float pvy = (py + 1.0f) * 0.5f * 127.0f;
            const float pvz = (pz + 1.0f) * 0.5f * 127.0f;

            const float fx = floorf(pvx), fy = floorf(pvy), fz = floorf(pvz);
            const float frx = pvx - fx, fry = pvy - fy, frz = pvz - fz;
            const int x0 = (int)fminf(fmaxf(fx, 0.0f), 127.0f);
            const int y0 = (int)fminf(fmaxf(fy, 0.0f), 127.0f);
            const int z0 = (int)fminf(fmaxf(fz, 0.0f), 127.0f);
            const int x1 = (int)fminf(fmaxf(ceilf(pvx), 0.0f), 127.0f);
            const int y1 = (int)fminf(fmaxf(ceilf(pvy), 0.0f), 127.0f);
            const int z1 = (int)fminf(fmaxf(ceilf(pvz), 0.0f), 127.0f);

            frv[si][0] = frx; frv[si][1] = fry; frv[si][2] = frz;
            xb2[si][0] = x0 << 14; xb2[si][1] = x1 << 14;
            yb2[si][0] = y0 << 7;  yb2[si][1] = y1 << 7;
            zb2[si][0] = z0;       zb2[si][1] = z1;

            // 8 independent density loads
            float dv[8];
            #pragma unroll
            for (int cx = 0; cx < 2; ++cx)
                #pragma unroll
                for (int cy = 0; cy < 2; ++cy)
                    #pragma unroll
                    for (int cz = 0; cz < 2; ++cz)
                        dv[cx*4+cy*2+cz] = density[xb2[si][cx] + yb2[si][cy] + zb2[si][cz]];

            const float wx0 = 1.0f - frx, wy0 = 1.0f - fry, wz0 = 1.0f - frz;
            sg  = (wx0*wy0*wz0) * dv[0];
            sg += (wx0*wy0*frz) * dv[1];
            sg += (wx0*fry*wz0) * dv[2];
            sg += (wx0*fry*frz) * dv[3];
            sg += (frx*wy0*wz0) * dv[4];
            sg += (frx*wy0*frz) * dv[5];
            sg += (frx*fry*wz0) * dv[6];
            sg += (frx*fry*frz) * dv[7];

            alpha2[si] = 1.0f - expf(-fmaxf(sg, 0.0f) * step);
        } else {
            alpha2[si] = 0.0f;
            frv[si][0] = frv[si][1] = frv[si][2] = 0.0f;
            xb2[si][0] = xb2[si][1] = 0;
            yb2[si][0] = yb2[si][1] = 0;
            zb2[si][0] = zb2[si][1] = 0;
        }
    }

    // ---- wave product-scan: trans_s = prod_{j<s} (1-alpha_j+1e-10) ----
    const float a0 = (1.0f - alpha2[0]) + 1e-10f;
    const float a1 = (1.0f - alpha2[1]) + 1e-10f;

    float incl = a0 * a1;
    #pragma unroll
    for (int off = 1; off < 64; off <<= 1) {
        const float v = __shfl_up(incl, off, 64);
        incl = (lane >= off) ? incl * v : incl;
    }
    float excl = __shfl_up(incl, 1, 64);
    excl = (lane == 0) ? 1.0f : excl;

    const float wgt0 = alpha2[0] * excl;
    const float wgt1 = alpha2[1] * (excl * a0);
    const float wgt[2] = {wgt0, wgt1};

    // ---- Phase B: SH gather only where weight > 0 ----
    float cr = 0.0f, cg = 0.0f, cb = 0.0f;

    #pragma unroll
    for (int si = 0; si < 2; ++si) {
        const float w = wgt[si];
        if (w > 0.0f) {
            const float frx = frv[si][0], fry = frv[si][1], frz = frv[si][2];
            const float wxv[2] = {1.0f - frx, frx};
            const float wyv[2] = {1.0f - fry, fry};
            const float wzv[2] = {1.0f - frz, frz};

            float r0 = 0.0f, r1 = 0.0f, r2 = 0.0f;
            #pragma unroll
            for (int cx = 0; cx < 2; ++cx) {
                #pragma unroll
                for (int cy = 0; cy < 2; ++cy) {
                    #pragma unroll
                    for (int cz = 0; cz < 2; ++cz) {
                        const float cw = wxv[cx] * wyv[cy] * wzv[cz];
                        const int base = xb2[si][cx] + yb2[si][cy] + zb2[si][cz];
                        const float* sp = sh + (long long)base * 27;
                        // 7 overlapped float4 loads covering floats 0..26
                        const float4 L0 = *(const float4*)(sp + 0);
                        const float4 L1 = *(const float4*)(sp + 4);
                        const float4 L2 = *(const float4*)(sp + 8);
                        const float4 L3 = *(const float4*)(sp + 12);
                        const float4 L4 = *(const float4*)(sp + 16);
                        const float4 L5 = *(const float4*)(sp + 20);
                        const float4 L6 = *(const float4*)(sp + 23);   // floats 23,24,25,26

                        const float d0 = L0.x*B0 + L0.y*B1 + L0.z*B2 + L0.w*B3
                                       + L1.x*B4 + L1.y*B5 + L1.z*B6 + L1.w*B7
                                       + L2.x*B8;
                        const float d1 = L2.y*B0 + L2.z*B1 + L2.w*B2
                                       + L3.x*B3 + L3.y*B4 + L3.z*B5 + L3.w*B6
                                       + L4.x*B7 + L4.y*B8;
                        const float d2 = L4.z*B0 + L4.w*B1
                                       + L5.x*B2 + L5.y*B3 + L5.z*B4 + L5.w*B5
                                       + L6.y*B6 + L6.z*B7 + L6.w*B8;

                        r0 = fmaf(cw, d0, r0);
                        r1 = fmaf(cw, d1, r1);
                        r2 = fmaf(cw, d2, r2);
                    }
                }
            }
            cr = fmaf(w, 1.0f / (1.0f + expf(-r0)), cr);
            cg = fmaf(w, 1.0f / (1.0f + expf(-r1)), cg);
            cb = fmaf(w, 1.0f / (1.0f + expf(-r2)), cb);
        }
    }

    // ---- wave reduction and write ----
    #pragma unroll
    for (int off = 32; off; off >>= 1) {
        cr += __shfl_down(cr, off, 64);
        cg += __shfl_down(cg, off, 64);
        cb += __shfl_down(cb, off, 64);
    }

    if (lane == 0) {
        out[ray*3+0] = cr;
        out[ray*3+1] = cg;
        out[ray*3+2] = cb;
    }
}

extern "C" void kernel_launch(void* const* d_in, const int* in_sizes, int n_in,
                              void* d_out, int out_size, void* d_ws, size_t ws_size,
                              hipStream_t stream) {
    const float* density = (const float*)d_in[0];
    const float* sh      = (const float*)d_in[1];
    const float* origins = (const float*)d_in[2];
    const float* dirs    = (const float*)d_in[3];
    const int*   ns_ptr  = (const int*)d_in[4];
    float* out = (float*)d_out;

    const int nrays = in_sizes[2] / 3;
    const int threads = 256;                       // 4 rays per block
    const int blocks = (nrays * 64 + threads - 1) / threads;
    plenoxel_render<<<blocks, threads, 0, stream>>>(density, sh, origins, dirs,
                                                    ns_ptr, out, nrays);
}